// Round 9
// baseline (536.251 us; speedup 1.0000x reference)
//
#include <hip/hip_runtime.h>
#include <hip/hip_fp16.h>

// GCN: N=100000 nodes (4 feats), E=3.2M edges, G=1024 graphs.
// out = mean-pool(tanh(gcn2(tanh(gcn1(embed(x)))))) @ W3.T + b3
//
// gcn_conv rewritten: u[i] = (h[i] @ W^T) * dinv[i];
// out[c] = dinv[c] * (sum_{edges r->c} u[r] + u[c]) + b   (self-loop folded in)
//
// R21: 2-pass LDS bucket sort (~55us: k_place+k_sort) replaced by a
// global-atomic counting sort using L2-resident counters (deg = 400KB):
//   k_hist: fire-and-forget atomicAdd(deg) while streaming col (no
//           latency exposure for non-returning atomics);
//   k_node1: per-256-node-block LDS scan + ONE atomicAdd(bucketCursor)
//           region reservation (no global scan; region order arbitrary),
//           writes rs/re/cur/dinv + fused u1q fp8 encode;
//   k_scatter: pos = atomicAdd(cur[c]); data[pos] = src. 4 indep
//           chains/thread, 3125 blocks.
// Aggs unchanged (R20: 4-lane/node, 4 gathers in flight, hoisted loads;
// R15b: u1 fp8 e4m3 x64 -> ONE uint4 gather/edge).
// Walls: harness 0xAA re-poison ~44us fixed (fills cap top-5);
// prior: L2 global-atomic wall ~19.4G txn/s -> 3.2M atomics ~ 0.2us.

constexpr int BLK  = 256;
constexpr float S8 = 64.0f;          // fp8 scale for u1 messages

// Histogram: stream col as int4, non-returning global atomics (no latency).
__global__ void k_hist(const int4* __restrict__ col4, int* __restrict__ deg, int nq) {
    int i = blockIdx.x * BLK + threadIdx.x;
    if (i >= nq) return;
    int4 c = col4[i];
    atomicAdd(&deg[c.x], 1);
    atomicAdd(&deg[c.y], 1);
    atomicAdd(&deg[c.z], 1);
    atomicAdd(&deg[c.w], 1);
}

// Per-block (256 nodes) LDS scan of degrees + one global cursor reservation
// -> rs/re/cur; dinv = rsqrt(deg+1); fused node1: u1 = fp8((embed(x) @ W1^T)
// * dinv * S8), one uint4 store.
__global__ void k_node1(const int* __restrict__ deg,
                        const float4* __restrict__ x,
                        const float* __restrict__ Wemb, const float* __restrict__ bemb,
                        const float* __restrict__ W1,
                        int* __restrict__ rs, int* __restrict__ re,
                        int* __restrict__ cur, float* __restrict__ dinv,
                        uint4* __restrict__ u1q, int* __restrict__ bucketCursor, int n) {
    __shared__ int wsum[4];
    __shared__ int sbase;
    int t = threadIdx.x;                        // 0..255
    int node = blockIdx.x * BLK + t;
    int lane = t & 63, w = t >> 6;
    int v = (node < n) ? deg[node] : 0;
    int sc = v;
#pragma unroll
    for (int o = 1; o < 64; o <<= 1) {
        int s = __shfl_up(sc, o, 64);
        if (lane >= o) sc += s;
    }
    if (lane == 63) wsum[w] = sc;
    __syncthreads();
    int pre = 0;
#pragma unroll
    for (int i = 0; i < 4; i++) if (i < w) pre += wsum[i];
    int excl = pre + sc - v;
    int total = wsum[0] + wsum[1] + wsum[2] + wsum[3];
    if (t == 0) sbase = atomicAdd(bucketCursor, total);
    __syncthreads();
    if (node >= n) return;
    int r0 = sbase + excl;
    rs[node] = r0;
    re[node] = r0 + v;
    cur[node] = r0;
    float d = rsqrtf((float)v + 1.0f);          // +1 self-loop
    dinv[node] = d;
    float4 xi = x[node];
    float h0[7];
#pragma unroll
    for (int j = 0; j < 4; j++) h0[j] = xi.x * Wemb[j] + bemb[j];
    h0[4] = xi.y; h0[5] = xi.z; h0[6] = xi.w;
    float s[16];
#pragma unroll
    for (int f = 0; f < 16; f++) {
        float tt = 0.0f;
#pragma unroll
        for (int j = 0; j < 7; j++) tt += h0[j] * W1[f * 7 + j];
        s[f] = tt * d * S8;                     // fp8 scale folded here
    }
    unsigned int w0, w1, w2, w3;
    w0 = __builtin_amdgcn_cvt_pk_fp8_f32(s[0],  s[1],  0,  false);
    w0 = __builtin_amdgcn_cvt_pk_fp8_f32(s[2],  s[3],  w0, true);
    w1 = __builtin_amdgcn_cvt_pk_fp8_f32(s[4],  s[5],  0,  false);
    w1 = __builtin_amdgcn_cvt_pk_fp8_f32(s[6],  s[7],  w1, true);
    w2 = __builtin_amdgcn_cvt_pk_fp8_f32(s[8],  s[9],  0,  false);
    w2 = __builtin_amdgcn_cvt_pk_fp8_f32(s[10], s[11], w2, true);
    w3 = __builtin_amdgcn_cvt_pk_fp8_f32(s[12], s[13], 0,  false);
    w3 = __builtin_amdgcn_cvt_pk_fp8_f32(s[14], s[15], w3, true);
    u1q[node] = make_uint4(w0, w1, w2, w3);
}

// Scatter: stream row+col, pos = atomicAdd(cur[dst]); data[pos] = src.
// 4 independent atomic->write chains per thread.
__global__ void k_scatter(const int4* __restrict__ row4, const int4* __restrict__ col4,
                          int* __restrict__ cur, unsigned int* __restrict__ data, int nq) {
    int i = blockIdx.x * BLK + threadIdx.x;
    if (i >= nq) return;
    int4 r = row4[i];
    int4 c = col4[i];
    int p0 = atomicAdd(&cur[c.x], 1);
    int p1 = atomicAdd(&cur[c.y], 1);
    int p2 = atomicAdd(&cur[c.z], 1);
    int p3 = atomicAdd(&cur[c.w], 1);
    data[p0] = (unsigned int)r.x;
    data[p1] = (unsigned int)r.y;
    data[p2] = (unsigned int)r.z;
    data[p3] = (unsigned int)r.w;
}

typedef float vfloat2 __attribute__((vector_size(8)));   // cvt_pk_f32_fp8 return type

// fp8 e4m3 uint4 (16 msgs) decode-accumulate into f32[16]
__device__ __forceinline__ void dec16_add(uint4 q, float* acc) {
#pragma unroll
    for (int w = 0; w < 4; w++) {
        unsigned int u = ((const unsigned int*)&q)[w];
        vfloat2 lo = __builtin_amdgcn_cvt_pk_f32_fp8(u, false);
        vfloat2 hi = __builtin_amdgcn_cvt_pk_f32_fp8(u, true);
        acc[4 * w + 0] += lo[0]; acc[4 * w + 1] += lo[1];
        acc[4 * w + 2] += hi[0]; acc[4 * w + 3] += hi[1];
    }
}

// Layer 1: 4 adjacent lanes/node, lane j takes edges s+j, s+j+4, ...
// 4 gathers in flight; self/dinv loads hoisted. Partials via shfl_xor(1,2).
// Epilogue (all 4 lanes compute, j==0 stores):
// u2h = fp16((tanh(dinv/S8*acc+b1) @ W2^T) * dinv), one uint4 store.
__global__ void k_agg1(const unsigned int* __restrict__ sorted,
                       const int* __restrict__ rs, const int* __restrict__ re,
                       const uint4* __restrict__ u1q, const float* __restrict__ dinv,
                       const float* __restrict__ b1, const float* __restrict__ W2,
                       uint4* __restrict__ u2q, int n) {
    int tt = blockIdx.x * BLK + threadIdx.x;
    int node = tt >> 2;
    int j = tt & 3;
    if (node >= n) return;
    int s = rs[node], e = re[node];
    float d = dinv[node];                       // hoisted: issues early
    uint4 qs = make_uint4(0, 0, 0, 0);
    if (j == 0) qs = u1q[node];                 // hoisted self-loop load
    float acc[16];
#pragma unroll
    for (int k = 0; k < 16; k++) acc[k] = 0.0f;
    int i = s + j;
    for (; i + 12 < e; i += 16) {               // 4 gathers in flight
        uint4 q0 = u1q[sorted[i]];
        uint4 q1 = u1q[sorted[i + 4]];
        uint4 q2 = u1q[sorted[i + 8]];
        uint4 q3 = u1q[sorted[i + 12]];
        dec16_add(q0, acc);
        dec16_add(q1, acc);
        dec16_add(q2, acc);
        dec16_add(q3, acc);
    }
    for (; i + 4 < e; i += 8) {                 // 2 in flight
        uint4 q0 = u1q[sorted[i]];
        uint4 q1 = u1q[sorted[i + 4]];
        dec16_add(q0, acc);
        dec16_add(q1, acc);
    }
    if (i < e) {
        uint4 q = u1q[sorted[i]];
        dec16_add(q, acc);
    }
    if (j == 0) dec16_add(qs, acc);             // self-loop term, added once
#pragma unroll
    for (int k = 0; k < 16; k++) {
        acc[k] += __shfl_xor(acc[k], 1, 64);
        acc[k] += __shfl_xor(acc[k], 2, 64);
    }
    float dS = d * (1.0f / S8);                 // undo fp8 scale
    float h1[16];
#pragma unroll
    for (int k = 0; k < 16; k++) h1[k] = tanhf(dS * acc[k] + b1[k]);
    float r[8];
#pragma unroll
    for (int g = 0; g < 8; g++) {
        float ttv = 0.0f;
#pragma unroll
        for (int k = 0; k < 16; k++) ttv += h1[k] * W2[g * 16 + k];
        r[g] = ttv * d;
    }
    if (j == 0) {
        union { __half2 h2[4]; uint4 u4; } pk;
#pragma unroll
        for (int q = 0; q < 4; q++) pk.h2[q] = __floats2half2_rn(r[2 * q], r[2 * q + 1]);
        u2q[node] = pk.u4;
    }
}

__device__ __forceinline__ void h16_add(uint4 q, float* acc) {
    const __half2* p = (const __half2*)&q;
#pragma unroll
    for (int k = 0; k < 4; k++) {
        float2 a = __half22float2(p[k]);
        acc[2 * k]     += a.x;
        acc[2 * k + 1] += a.y;
    }
}

// Layer 2 + POOL fused: 4 adjacent lanes/node (16 nodes/wave), 4 gathers in
// flight; self/dinv/batch hoisted; partials via shfl_xor(1,2); h2 on base
// lanes; stride-4 wave-segmented reduction over sorted batch (offsets
// 4..32), segment heads atomicAdd 8 features + count into pooled/cnt.
__global__ void k_agg2_pool(const unsigned int* __restrict__ sorted,
                            const int* __restrict__ rs, const int* __restrict__ re,
                            const uint4* __restrict__ u2q, const float* __restrict__ dinv,
                            const float* __restrict__ b2, const int* __restrict__ batch,
                            float* __restrict__ pooled, float* __restrict__ cnt, int n) {
    int tt = blockIdx.x * BLK + threadIdx.x;
    int node = tt >> 2;
    int j = tt & 3;
    int lane = threadIdx.x & 63;
    bool valid = node < n;
    float h[8];
#pragma unroll
    for (int k = 0; k < 8; k++) h[k] = 0.0f;
    int g = -1;
    float c = 0.0f;
    if (valid) {
        int s = rs[node], e = re[node];
        float d = dinv[node];                   // hoisted
        uint4 qs = make_uint4(0, 0, 0, 0);
        int gq = 0;
        if (j == 0) {                           // hoisted self + batch loads
            qs = u2q[node];
            gq = batch[node];
        }
        float acc[8];
#pragma unroll
        for (int k = 0; k < 8; k++) acc[k] = 0.0f;
        int i = s + j;
        for (; i + 12 < e; i += 16) {           // 4 gathers in flight
            uint4 q0 = u2q[sorted[i]];
            uint4 q1 = u2q[sorted[i + 4]];
            uint4 q2 = u2q[sorted[i + 8]];
            uint4 q3 = u2q[sorted[i + 12]];
            h16_add(q0, acc);
            h16_add(q1, acc);
            h16_add(q2, acc);
            h16_add(q3, acc);
        }
        for (; i + 4 < e; i += 8) {             // 2 in flight
            uint4 q0 = u2q[sorted[i]];
            uint4 q1 = u2q[sorted[i + 4]];
            h16_add(q0, acc);
            h16_add(q1, acc);
        }
        if (i < e) {
            uint4 q = u2q[sorted[i]];
            h16_add(q, acc);
        }
        if (j == 0) h16_add(qs, acc);           // self-loop, added once
#pragma unroll
        for (int k = 0; k < 8; k++) {
            acc[k] += __shfl_xor(acc[k], 1, 64);
            acc[k] += __shfl_xor(acc[k], 2, 64);
        }
        if (j == 0) {
#pragma unroll
            for (int k = 0; k < 8; k++) h[k] = tanhf(d * acc[k] + b2[k]);
            g = gq;
            c = 1.0f;
        }
    }
    // stride-4 segmented reduction: base lanes (j==0) hold 16 consecutive
    // nodes per wave; offsets 4..32 only ever read base lanes.
#pragma unroll
    for (int off = 4; off < 64; off <<= 1) {
        int gn = __shfl_down(g, off, 64);
        float cn = __shfl_down(c, off, 64);
        float hn[8];
#pragma unroll
        for (int k = 0; k < 8; k++) hn[k] = __shfl_down(h[k], off, 64);
        bool take = (lane + off < 64) && (gn == g);
        if (take) {
            c += cn;
#pragma unroll
            for (int k = 0; k < 8; k++) h[k] += hn[k];
        }
    }
    int gprev = __shfl_up(g, 4, 64);
    bool head = valid && (j == 0) && (lane == 0 || gprev != g);
    if (head) {
#pragma unroll
        for (int k = 0; k < 8; k++) atomicAdd(&pooled[g * 8 + k], h[k]);
        atomicAdd(&cnt[g], c);
    }
}

// Tiny head: out[g] = dot(pooled[g], W3) / max(cnt,1) + b3
__global__ void k_out(const float* __restrict__ pooled, const float* __restrict__ cnt,
                      const float* __restrict__ W3, const float* __restrict__ b3,
                      float* __restrict__ out, int G) {
    int g = blockIdx.x * BLK + threadIdx.x;
    if (g >= G) return;
    float c = fmaxf(cnt[g], 1.0f);
    float t = 0.0f;
#pragma unroll
    for (int k = 0; k < 8; k++) t += pooled[g * 8 + k] * W3[k];
    out[g] = t / c + b3[0];
}

extern "C" void kernel_launch(void* const* d_in, const int* in_sizes, int n_in,
                              void* d_out, int out_size, void* d_ws, size_t ws_size,
                              hipStream_t stream) {
    const float* x    = (const float*)d_in[0];
    const int*   ei   = (const int*)d_in[1];
    const int*   batch= (const int*)d_in[2];
    const float* Wemb = (const float*)d_in[3];
    const float* bemb = (const float*)d_in[4];
    const float* W1   = (const float*)d_in[5];
    const float* b1   = (const float*)d_in[6];
    const float* W2   = (const float*)d_in[7];
    const float* b2   = (const float*)d_in[8];
    const float* W3   = (const float*)d_in[9];
    const float* b3   = (const float*)d_in[10];
    float* out = (float*)d_out;

    const int n = in_sizes[2];        // 100000
    const int E = in_sizes[1] / 2;    // 3200000
    const int G = out_size;           // 1024
    const int* row = ei;
    const int* col = ei + E;

    // workspace (4B words): dinv[n] | u1q(8n reserved, 4n used: fp8 16B/node) |
    //   u2h(4n) | rs[n] | re[n] | cur[n] | deg[n] | bucketCursor+pad[64] |
    //   pooled[8G] | cnt[G] | data[E]  (~19.7 MB)
    float* ws    = (float*)d_ws;
    float* dinv  = ws;                       // n
    uint4* u1q   = (uint4*)(ws + n);         // 4n words used (16 fp8/node)
    __half* u2h  = (__half*)(ws + 9 * n);    // 4n words (8 halves/node)
    int* rs      = (int*)(ws + 13 * n);      // n
    int* re      = rs + n;                   // n
    int* cur     = re + n;                   // n
    int* deg     = cur + n;                  // n         (memset from here)
    int* bucketCursor = deg + n;             // 1 (+63 pad)
    float* pooled  = (float*)(bucketCursor + 64);   // 8G
    float* cnt     = pooled + 8 * G;                // G
    unsigned int* data = (unsigned int*)(cnt + G);  // E

    int nq    = E / 4;                       // 800000 int4s
    int gridQ = (nq + BLK - 1) / BLK;        // 3125 blocks
    int gridN = (n + BLK - 1) / BLK;         // 391 blocks
    int gridA = (4 * n + BLK - 1) / BLK;     // 1563 blocks, 4 lanes/node

    // one memset zeroes deg + bucketCursor + pooled + cnt (contiguous, ~437KB)
    hipMemsetAsync(deg, 0, (n + 64 + 9 * G) * sizeof(int), stream);
    k_hist<<<gridQ, BLK, 0, stream>>>((const int4*)col, deg, nq);
    k_node1<<<gridN, BLK, 0, stream>>>(deg, (const float4*)x, Wemb, bemb, W1,
                                       rs, re, cur, dinv, u1q, bucketCursor, n);
    k_scatter<<<gridQ, BLK, 0, stream>>>((const int4*)row, (const int4*)col,
                                         cur, data, nq);
    k_agg1<<<gridA, BLK, 0, stream>>>(data, rs, re, u1q,
                                      dinv, b1, W2, (uint4*)u2h, n);
    k_agg2_pool<<<gridA, BLK, 0, stream>>>(data, rs, re,
                                           (const uint4*)u2h, dinv, b2,
                                           batch, pooled, cnt, n);
    k_out<<<(G + BLK - 1) / BLK, BLK, 0, stream>>>(pooled, cnt, W3, b3, out, G);
}

// Round 10
// 184.739 us; speedup vs baseline: 2.9027x; 2.9027x over previous
//
#include <hip/hip_runtime.h>
#include <hip/hip_fp16.h>

// GCN: N=100000 nodes (4 feats), E=3.2M edges, G=1024 graphs.
// out = mean-pool(tanh(gcn2(tanh(gcn1(embed(x)))))) @ W3.T + b3
//
// gcn_conv rewritten: u[i] = (h[i] @ W^T) * dinv[i];
// out[c] = dinv[c] * (sum_{edges r->c} u[r] + u[c]) + b   (self-loop folded in)
//
// R22: revert R21 (global-atomic scatter = 295us: 3.2M scattered 4B writes
// -> 194MB HBM partial-line writebacks, 15x amplification; LDS staging IS
// the write-amp defense). R20 base (measured 180.0) + two levers:
// (1) k_place rank replication x4 -> x8 (matches k_sort; grid is only
//     ~2 blocks/CU so the 57KB LDS doesn't bind occupancy);
// (2) memset shrunk to bucketCnt; pooled/cnt zeroed by k_agg1's first
//     36 blocks (R17-tested, runs before k_agg2_pool on-stream).
// R20: x8 k_sort bins, 4-deep agg ILP, hoisted per-node loads.
// R19: stageB direct copy-out. R16: 4-lane aggs. R15b: u1 fp8 e4m3 (x64).
// Walls: harness 0xAA re-poison ~44us fixed; fills cap top-5.

constexpr int BLK  = 256;
constexpr int NPB  = 256;            // dst nodes per bucket (dloc = 8 bits)
constexpr int NBMX = 512;            // padded bin count (NB = 391)
constexpr int CAPB = 9216;           // slots/bucket; mean 8184, sigma ~90
constexpr int PBLK = 512;            // k_place block size
constexpr int CAPS = 6144;           // k_place chunk = PBLK * EPT
constexpr int EPT  = 12;             // edges/thread in k_place
constexpr int SBLK = 512;            // k_sort block size
constexpr int NIT4 = 5;              // uint4 iters: ceil(CAPB/(SBLK*4))
constexpr float S8 = 64.0f;          // fp8 scale for u1 messages

// Single-pass placement, ONE LDS-atomic pass (x8 replicated bins):
// o = atomicAdd(&pos[rep][b],1) is both offset and histogram; scan merges
// replicas -> sstart + per-replica bases; reserve global space; stage
// (entry + bucket id); direct-lookup copy-out. entry = (dloc<<17) | src.
// meta = (rep:3)@22 | (b:9)@13 | (o:13)@0 ; invalid = -1.
__global__ void k_place(const int4* __restrict__ row4, const int4* __restrict__ col4,
                        int* __restrict__ bucketCnt, unsigned int* __restrict__ data,
                        int E, int NB) {
    __shared__ unsigned int stage[CAPS];                    // 24.6 KB
    __shared__ unsigned short stageB[CAPS];                 // 12.3 KB
    __shared__ int pos[8][NBMX];                            // 16 KB
    __shared__ int sstart[NBMX], lbase[NBMX];               // 4 KB
    __shared__ int wsum[8];
    int t = threadIdx.x;                        // 0..511
    int lane = t & 63, w = t >> 6;
    int rep = (lane >> 3) & 7;                  // x8 replica by 8-lane group
    int begin = blockIdx.x * CAPS;
    int end = min(E, begin + CAPS);
    int csize = end - begin;                    // multiple of 4
    int q0 = begin >> 2, q1 = end >> 2;
#pragma unroll
    for (int rr = 0; rr < 8; rr++) pos[rr][t] = 0;
    __syncthreads();
    unsigned int ent[EPT];
    int meta[EPT];
#pragma unroll
    for (int it = 0; it < EPT / 4; it++) {
        int i = q0 + t + it * PBLK;
        bool ok = i < q1;
        int4 c = ok ? col4[i] : make_int4(0, 0, 0, 0);
        int4 r = ok ? row4[i] : make_int4(0, 0, 0, 0);
#pragma unroll
        for (int k = 0; k < 4; k++) {
            int cc = ((const int*)&c)[k];
            int rr = ((const int*)&r)[k];
            int b = cc >> 8;
            int o = ok ? atomicAdd(&pos[rep][b], 1) : 0;
            ent[it * 4 + k] = ((unsigned int)(cc & 255) << 17) | (unsigned int)rr;
            meta[it * 4 + k] = ok ? ((rep << 22) | (b << 13) | o) : -1;
        }
    }
    __syncthreads();
    // scan 512 bins, thread owns bin t; merge 8 replicas
    int p[8];
    int v = 0;
#pragma unroll
    for (int r = 0; r < 8; r++) { p[r] = pos[r][t]; v += p[r]; }
    int sc = v;
#pragma unroll
    for (int off = 1; off < 64; off <<= 1) {
        int o = __shfl_up(sc, off, 64);
        if (lane >= off) sc += o;
    }
    if (lane == 63) wsum[w] = sc;
    __syncthreads();
    int pre = 0;
#pragma unroll
    for (int i = 0; i < 8; i++) if (i < w) pre += wsum[i];
    int excl = sc + pre - v;
    sstart[t] = excl;
    lbase[t] = v ? atomicAdd(&bucketCnt[t], v) : 0;
    // per-replica base offsets within bin t (overwrite counters)
    int run = 0;
#pragma unroll
    for (int r = 0; r < 8; r++) { pos[r][t] = run; run += p[r]; }
    __syncthreads();
#pragma unroll
    for (int k = 0; k < EPT; k++) {
        int m = meta[k];
        if (m >= 0) {
            int rr = (m >> 22) & 7;
            int b  = (m >> 13) & 0x1FF;
            int o  = m & 0x1FFF;
            int idx = sstart[b] + pos[rr][b] + o;
            stage[idx]  = ent[k];
            stageB[idx] = (unsigned short)b;
        }
    }
    __syncthreads();
    for (int k = t; k < csize; k += PBLK) {
        int b = stageB[k];
        data[(unsigned int)b * CAPB + (unsigned int)(lbase[b] + (k - sstart[b]))] = stage[k];
    }
}

// Per-bucket one-pass counting sort (edges in registers via uint4 loads,
// x8 replicated bins, scatter straight to the L2-resident bucket region)
// + dinv + rs/re + fused node1 (u1 encoded fp8 e4m3 x64). BLK=512.
__global__ void k_sort_node1(unsigned int* __restrict__ data,
                             const int* __restrict__ bucketCnt,
                             const float4* __restrict__ x,
                             const float* __restrict__ Wemb, const float* __restrict__ bemb,
                             const float* __restrict__ W1,
                             int* __restrict__ rs, int* __restrict__ re,
                             float* __restrict__ dinv, uint4* __restrict__ u1q, int n) {
    __shared__ int pos[8][NPB], startl[NPB];    // 8 KB + 1 KB
    __shared__ int wsum[4];
    int b = blockIdx.x;
    int t = threadIdx.x;                        // 0..511
    int lane = t & 63;
    int rep = (lane >> 3) & 7;                  // x8 replica by 8-lane group
    int base = b * CAPB;
    int cnt = min(bucketCnt[b], CAPB);
#pragma unroll
    for (int z = 0; z < 4; z++) ((int*)pos)[t + z * SBLK] = 0;   // 8*256 ints
    __syncthreads();
    const uint4* data4 = (const uint4*)(data + base);   // base = b*9216, 16B aligned
    unsigned int ent[NIT4 * 4];                 // src (17 bits)
    int off[NIT4 * 4];                          // (rep<<22)|(dloc<<14)|o
#pragma unroll
    for (int it = 0; it < NIT4; it++) {
        int i4 = t + it * SBLK;                 // quad index
        int i = i4 * 4;
        uint4 p4 = (i < cnt) ? data4[i4] : make_uint4(0, 0, 0, 0);
#pragma unroll
        for (int k = 0; k < 4; k++) {
            int idx = it * 4 + k;
            if (i + k < cnt) {
                unsigned int p = ((const unsigned int*)&p4)[k];
                int dloc = (int)(p >> 17);
                int o = atomicAdd(&pos[rep][dloc], 1);
                ent[idx] = p & 0x1FFFF;
                off[idx] = (rep << 22) | (dloc << 14) | o;
            } else off[idx] = -1;
        }
    }
    __syncthreads();
    int node = b * NPB + t;
    float d = 0.0f;
    if (t < NPB) {
        int w = t >> 6;
        int p[8];
        int v = 0;
#pragma unroll
        for (int r = 0; r < 8; r++) { p[r] = pos[r][t]; v += p[r]; }
        int sc = v;
#pragma unroll
        for (int o = 1; o < 64; o <<= 1) {
            int s = __shfl_up(sc, o, 64);
            if (lane >= o) sc += s;
        }
        if (lane == 63) wsum[w] = sc;
        __syncthreads();
        int pre = 0;
#pragma unroll
        for (int i = 0; i < 4; i++) if (i < w) pre += wsum[i];
        int excl = sc + pre - v;
        startl[t] = excl;
        int run = 0;
#pragma unroll
        for (int r = 0; r < 8; r++) { pos[r][t] = run; run += p[r]; }
        if (node < n) {
            rs[node] = base + excl;
            re[node] = base + excl + v;
            d = rsqrtf((float)v + 1.0f);        // +1 self-loop
            dinv[node] = d;
        }
    } else {
        __syncthreads();
    }
    __syncthreads();
#pragma unroll
    for (int it = 0; it < NIT4 * 4; it++) {
        int m = off[it];
        if (m >= 0) {
            int rr = (m >> 22) & 7;
            int dl = (m >> 14) & 255;
            int o  = m & 0x3FFF;
            data[base + startl[dl] + pos[rr][dl] + o] = ent[it];
        }
    }
    if (t < NPB && node < n) {
        float4 xi = x[node];
        float h0[7];
#pragma unroll
        for (int j = 0; j < 4; j++) h0[j] = xi.x * Wemb[j] + bemb[j];
        h0[4] = xi.y; h0[5] = xi.z; h0[6] = xi.w;
        float s[16];
#pragma unroll
        for (int f = 0; f < 16; f++) {
            float tt = 0.0f;
#pragma unroll
            for (int j = 0; j < 7; j++) tt += h0[j] * W1[f * 7 + j];
            s[f] = tt * d * S8;                 // fp8 scale folded here
        }
        unsigned int w0, w1, w2, w3;
        w0 = __builtin_amdgcn_cvt_pk_fp8_f32(s[0],  s[1],  0,  false);
        w0 = __builtin_amdgcn_cvt_pk_fp8_f32(s[2],  s[3],  w0, true);
        w1 = __builtin_amdgcn_cvt_pk_fp8_f32(s[4],  s[5],  0,  false);
        w1 = __builtin_amdgcn_cvt_pk_fp8_f32(s[6],  s[7],  w1, true);
        w2 = __builtin_amdgcn_cvt_pk_fp8_f32(s[8],  s[9],  0,  false);
        w2 = __builtin_amdgcn_cvt_pk_fp8_f32(s[10], s[11], w2, true);
        w3 = __builtin_amdgcn_cvt_pk_fp8_f32(s[12], s[13], 0,  false);
        w3 = __builtin_amdgcn_cvt_pk_fp8_f32(s[14], s[15], w3, true);
        u1q[node] = make_uint4(w0, w1, w2, w3);
    }
}

typedef float vfloat2 __attribute__((vector_size(8)));   // cvt_pk_f32_fp8 return type

// fp8 e4m3 uint4 (16 msgs) decode-accumulate into f32[16]
__device__ __forceinline__ void dec16_add(uint4 q, float* acc) {
#pragma unroll
    for (int w = 0; w < 4; w++) {
        unsigned int u = ((const unsigned int*)&q)[w];
        vfloat2 lo = __builtin_amdgcn_cvt_pk_f32_fp8(u, false);
        vfloat2 hi = __builtin_amdgcn_cvt_pk_f32_fp8(u, true);
        acc[4 * w + 0] += lo[0]; acc[4 * w + 1] += lo[1];
        acc[4 * w + 2] += hi[0]; acc[4 * w + 3] += hi[1];
    }
}

// Layer 1: 4 adjacent lanes/node, lane j takes edges s+j, s+j+4, ...
// 4 gathers in flight; self/dinv loads hoisted. Partials via shfl_xor(1,2).
// First 36 blocks also zero pooled/cnt for the downstream pool.
// Epilogue (all 4 lanes compute, j==0 stores):
// u2h = fp16((tanh(dinv/S8*acc+b1) @ W2^T) * dinv), one uint4 store.
__global__ void k_agg1(const unsigned int* __restrict__ sorted,
                       const int* __restrict__ rs, const int* __restrict__ re,
                       const uint4* __restrict__ u1q, const float* __restrict__ dinv,
                       const float* __restrict__ b1, const float* __restrict__ W2,
                       uint4* __restrict__ u2q, float* __restrict__ pooledz,
                       int n, int G) {
    int tt = blockIdx.x * BLK + threadIdx.x;
    if (tt < 9 * G) pooledz[tt] = 0.0f;         // pooled[8G] + cnt[G] contiguous
    int node = tt >> 2;
    int j = tt & 3;
    if (node >= n) return;
    int s = rs[node], e = re[node];
    float d = dinv[node];                       // hoisted: issues early
    uint4 qs = make_uint4(0, 0, 0, 0);
    if (j == 0) qs = u1q[node];                 // hoisted self-loop load
    float acc[16];
#pragma unroll
    for (int k = 0; k < 16; k++) acc[k] = 0.0f;
    int i = s + j;
    for (; i + 12 < e; i += 16) {               // 4 gathers in flight
        uint4 q0 = u1q[sorted[i]];
        uint4 q1 = u1q[sorted[i + 4]];
        uint4 q2 = u1q[sorted[i + 8]];
        uint4 q3 = u1q[sorted[i + 12]];
        dec16_add(q0, acc);
        dec16_add(q1, acc);
        dec16_add(q2, acc);
        dec16_add(q3, acc);
    }
    for (; i + 4 < e; i += 8) {                 // 2 in flight
        uint4 q0 = u1q[sorted[i]];
        uint4 q1 = u1q[sorted[i + 4]];
        dec16_add(q0, acc);
        dec16_add(q1, acc);
    }
    if (i < e) {
        uint4 q = u1q[sorted[i]];
        dec16_add(q, acc);
    }
    if (j == 0) dec16_add(qs, acc);             // self-loop term, added once
#pragma unroll
    for (int k = 0; k < 16; k++) {
        acc[k] += __shfl_xor(acc[k], 1, 64);
        acc[k] += __shfl_xor(acc[k], 2, 64);
    }
    float dS = d * (1.0f / S8);                 // undo fp8 scale
    float h1[16];
#pragma unroll
    for (int k = 0; k < 16; k++) h1[k] = tanhf(dS * acc[k] + b1[k]);
    float r[8];
#pragma unroll
    for (int g = 0; g < 8; g++) {
        float ttv = 0.0f;
#pragma unroll
        for (int k = 0; k < 16; k++) ttv += h1[k] * W2[g * 16 + k];
        r[g] = ttv * d;
    }
    if (j == 0) {
        union { __half2 h2[4]; uint4 u4; } pk;
#pragma unroll
        for (int q = 0; q < 4; q++) pk.h2[q] = __floats2half2_rn(r[2 * q], r[2 * q + 1]);
        u2q[node] = pk.u4;
    }
}

__device__ __forceinline__ void h16_add(uint4 q, float* acc) {
    const __half2* p = (const __half2*)&q;
#pragma unroll
    for (int k = 0; k < 4; k++) {
        float2 a = __half22float2(p[k]);
        acc[2 * k]     += a.x;
        acc[2 * k + 1] += a.y;
    }
}

// Layer 2 + POOL fused: 4 adjacent lanes/node (16 nodes/wave), 4 gathers in
// flight; self/dinv/batch hoisted; partials via shfl_xor(1,2); h2 on base
// lanes; stride-4 wave-segmented reduction over sorted batch (offsets
// 4..32), segment heads atomicAdd 8 features + count into pooled/cnt.
__global__ void k_agg2_pool(const unsigned int* __restrict__ sorted,
                            const int* __restrict__ rs, const int* __restrict__ re,
                            const uint4* __restrict__ u2q, const float* __restrict__ dinv,
                            const float* __restrict__ b2, const int* __restrict__ batch,
                            float* __restrict__ pooled, float* __restrict__ cnt, int n) {
    int tt = blockIdx.x * BLK + threadIdx.x;
    int node = tt >> 2;
    int j = tt & 3;
    int lane = threadIdx.x & 63;
    bool valid = node < n;
    float h[8];
#pragma unroll
    for (int k = 0; k < 8; k++) h[k] = 0.0f;
    int g = -1;
    float c = 0.0f;
    if (valid) {
        int s = rs[node], e = re[node];
        float d = dinv[node];                   // hoisted
        uint4 qs = make_uint4(0, 0, 0, 0);
        int gq = 0;
        if (j == 0) {                           // hoisted self + batch loads
            qs = u2q[node];
            gq = batch[node];
        }
        float acc[8];
#pragma unroll
        for (int k = 0; k < 8; k++) acc[k] = 0.0f;
        int i = s + j;
        for (; i + 12 < e; i += 16) {           // 4 gathers in flight
            uint4 q0 = u2q[sorted[i]];
            uint4 q1 = u2q[sorted[i + 4]];
            uint4 q2 = u2q[sorted[i + 8]];
            uint4 q3 = u2q[sorted[i + 12]];
            h16_add(q0, acc);
            h16_add(q1, acc);
            h16_add(q2, acc);
            h16_add(q3, acc);
        }
        for (; i + 4 < e; i += 8) {             // 2 in flight
            uint4 q0 = u2q[sorted[i]];
            uint4 q1 = u2q[sorted[i + 4]];
            h16_add(q0, acc);
            h16_add(q1, acc);
        }
        if (i < e) {
            uint4 q = u2q[sorted[i]];
            h16_add(q, acc);
        }
        if (j == 0) h16_add(qs, acc);           // self-loop, added once
#pragma unroll
        for (int k = 0; k < 8; k++) {
            acc[k] += __shfl_xor(acc[k], 1, 64);
            acc[k] += __shfl_xor(acc[k], 2, 64);
        }
        if (j == 0) {
#pragma unroll
            for (int k = 0; k < 8; k++) h[k] = tanhf(d * acc[k] + b2[k]);
            g = gq;
            c = 1.0f;
        }
    }
    // stride-4 segmented reduction: base lanes (j==0) hold 16 consecutive
    // nodes per wave; offsets 4..32 only ever read base lanes.
#pragma unroll
    for (int off = 4; off < 64; off <<= 1) {
        int gn = __shfl_down(g, off, 64);
        float cn = __shfl_down(c, off, 64);
        float hn[8];
#pragma unroll
        for (int k = 0; k < 8; k++) hn[k] = __shfl_down(h[k], off, 64);
        bool take = (lane + off < 64) && (gn == g);
        if (take) {
            c += cn;
#pragma unroll
            for (int k = 0; k < 8; k++) h[k] += hn[k];
        }
    }
    int gprev = __shfl_up(g, 4, 64);
    bool head = valid && (j == 0) && (lane == 0 || gprev != g);
    if (head) {
#pragma unroll
        for (int k = 0; k < 8; k++) atomicAdd(&pooled[g * 8 + k], h[k]);
        atomicAdd(&cnt[g], c);
    }
}

// Tiny head: out[g] = dot(pooled[g], W3) / max(cnt,1) + b3
__global__ void k_out(const float* __restrict__ pooled, const float* __restrict__ cnt,
                      const float* __restrict__ W3, const float* __restrict__ b3,
                      float* __restrict__ out, int G) {
    int g = blockIdx.x * BLK + threadIdx.x;
    if (g >= G) return;
    float c = fmaxf(cnt[g], 1.0f);
    float t = 0.0f;
#pragma unroll
    for (int k = 0; k < 8; k++) t += pooled[g * 8 + k] * W3[k];
    out[g] = t / c + b3[0];
}

extern "C" void kernel_launch(void* const* d_in, const int* in_sizes, int n_in,
                              void* d_out, int out_size, void* d_ws, size_t ws_size,
                              hipStream_t stream) {
    const float* x    = (const float*)d_in[0];
    const int*   ei   = (const int*)d_in[1];
    const int*   batch= (const int*)d_in[2];
    const float* Wemb = (const float*)d_in[3];
    const float* bemb = (const float*)d_in[4];
    const float* W1   = (const float*)d_in[5];
    const float* b1   = (const float*)d_in[6];
    const float* W2   = (const float*)d_in[7];
    const float* b2   = (const float*)d_in[8];
    const float* W3   = (const float*)d_in[9];
    const float* b3   = (const float*)d_in[10];
    float* out = (float*)d_out;

    const int n = in_sizes[2];        // 100000
    const int E = in_sizes[1] / 2;    // 3200000
    const int G = out_size;           // 1024
    const int* row = ei;
    const int* col = ei + E;
    const int NB = (n + NPB - 1) / NPB;   // 391

    // workspace (4B words): dinv[n] | u1q(8n reserved, 4n used: fp8 16B/node) |
    //   u2h(4n) | rs[n] | re[n] | bucketCnt[NBMX] | pooled[8G] | cnt[G] |
    //   data[NB*CAPB]  (~20.5 MB)
    float* ws    = (float*)d_ws;
    float* dinv  = ws;                       // n
    uint4* u1q   = (uint4*)(ws + n);         // 4n words used (16 fp8/node)
    __half* u2h  = (__half*)(ws + 9 * n);    // 4n words (8 halves/node)
    int* rs      = (int*)(ws + 13 * n);      // n
    int* re      = rs + n;                   // n
    int* bucketCnt = re + n;                 // NBMX
    float* pooled  = (float*)(bucketCnt + NBMX);   // 8G
    float* cnt     = pooled + 8 * G;               // G
    unsigned int* data = (unsigned int*)(cnt + G); // NB*CAPB

    int gridP = (E + CAPS - 1) / CAPS;       // 521 blocks, chunk = 6144
    int gridA = (4 * n + BLK - 1) / BLK;     // 1563 blocks, 4 lanes/node

    // small memset: bucketCnt only; pooled/cnt zeroed in k_agg1
    hipMemsetAsync(bucketCnt, 0, NBMX * sizeof(int), stream);
    k_place<<<gridP, PBLK, 0, stream>>>((const int4*)row, (const int4*)col,
                                        bucketCnt, data, E, NB);
    k_sort_node1<<<NB, SBLK, 0, stream>>>(data, bucketCnt, (const float4*)x,
                                          Wemb, bemb, W1, rs, re, dinv, u1q, n);
    k_agg1<<<gridA, BLK, 0, stream>>>(data, rs, re, u1q,
                                      dinv, b1, W2, (uint4*)u2h, pooled, n, G);
    k_agg2_pool<<<gridA, BLK, 0, stream>>>(data, rs, re,
                                           (const uint4*)u2h, dinv, b2,
                                           batch, pooled, cnt, n);
    k_out<<<(G + BLK - 1) / BLK, BLK, 0, stream>>>(pooled, cnt, W3, b3, out, G);
}

// Round 11
// 180.588 us; speedup vs baseline: 2.9695x; 1.0230x over previous
//
#include <hip/hip_runtime.h>
#include <hip/hip_fp16.h>

// GCN: N=100000 nodes (4 feats), E=3.2M edges, G=1024 graphs.
// out = mean-pool(tanh(gcn2(tanh(gcn1(embed(x)))))) @ W3.T + b3
//
// gcn_conv rewritten: u[i] = (h[i] @ W^T) * dinv[i];
// out[c] = dinv[c] * (sum_{edges r->c} u[r] + u[c]) + b   (self-loop folded in)
//
// R23 = exact R20 (session best, measured 179.97us). R22's bundle (k_place
// x8 + memset shrink) regressed +4.7us -> reverted. Structure ledger:
// - R21 global-atomic sort: scatter 295us (194MB partial-line writebacks,
//   15x write amplification) -> LDS bucket staging IS the defense. KEEP.
// - R18/R5 8-lane aggs: regress (dup epilogue + clamped-gather waste). 4-lane.
// - R17/R4 fused k_out w/ threadfence: +35us convoy. Separate k_out. KEEP.
// R20: x8 k_sort rank bins, 4-deep agg ILP, hoisted per-node loads.
// R19: x4 k_place rank bins + stageB direct copy-out (no binary search).
// R16: 4 lanes/node aggs, shfl_xor(1,2) combine, stride-4 segmented pool.
// R15b: u1 fp8 e4m3 (x64, HW cvt_pk) -> ONE uint4 gather/edge.
// Walls: harness 0xAA re-poison ~44us fixed (caps top-5); agg gathers at
// ~19.4G txn/s L2 wall; sort machinery ~55us (2 staged passes, LDS atomics).

constexpr int BLK  = 256;
constexpr int NPB  = 256;            // dst nodes per bucket (dloc = 8 bits)
constexpr int NBMX = 512;            // padded bin count (NB = 391)
constexpr int CAPB = 9216;           // slots/bucket; mean 8184, sigma ~90
constexpr int PBLK = 512;            // k_place block size
constexpr int CAPS = 6144;           // k_place chunk = PBLK * EPT
constexpr int EPT  = 12;             // edges/thread in k_place
constexpr int SBLK = 512;            // k_sort block size
constexpr int NIT4 = 5;              // uint4 iters: ceil(CAPB/(SBLK*4))
constexpr float S8 = 64.0f;          // fp8 scale for u1 messages

// Single-pass placement, ONE LDS-atomic pass (x4 replicated bins):
// o = atomicAdd(&pos[rep][b],1) is both offset and histogram; scan merges
// replicas -> sstart + per-replica bases; reserve global space; stage
// (entry + bucket id); direct-lookup copy-out. entry = (dloc<<17) | src.
__global__ void k_place(const int4* __restrict__ row4, const int4* __restrict__ col4,
                        int* __restrict__ bucketCnt, unsigned int* __restrict__ data,
                        int E, int NB) {
    __shared__ unsigned int stage[CAPS];                    // 24.6 KB
    __shared__ unsigned short stageB[CAPS];                 // 12.3 KB
    __shared__ int pos[4][NBMX];                            // 8 KB
    __shared__ int sstart[NBMX], lbase[NBMX];               // 4 KB
    __shared__ int wsum[8];
    int t = threadIdx.x;                        // 0..511
    int lane = t & 63, w = t >> 6;
    int rep = (lane >> 4) & 3;                  // replica by lane group
    int begin = blockIdx.x * CAPS;
    int end = min(E, begin + CAPS);
    int csize = end - begin;                    // multiple of 4
    int q0 = begin >> 2, q1 = end >> 2;
#pragma unroll
    for (int rr = 0; rr < 4; rr++) pos[rr][t] = 0;
    __syncthreads();
    unsigned int ent[EPT];
    int meta[EPT];
#pragma unroll
    for (int it = 0; it < EPT / 4; it++) {
        int i = q0 + t + it * PBLK;
        bool ok = i < q1;
        int4 c = ok ? col4[i] : make_int4(0, 0, 0, 0);
        int4 r = ok ? row4[i] : make_int4(0, 0, 0, 0);
#pragma unroll
        for (int k = 0; k < 4; k++) {
            int cc = ((const int*)&c)[k];
            int rr = ((const int*)&r)[k];
            int b = cc >> 8;
            int o = ok ? atomicAdd(&pos[rep][b], 1) : 0;
            ent[it * 4 + k] = ((unsigned int)(cc & 255) << 17) | (unsigned int)rr;
            // meta = (rep<<22) | (b<<13) | o   (b<512: 9b, o<6144: 13b)
            meta[it * 4 + k] = ok ? ((rep << 22) | (b << 13) | o) : -1;
        }
    }
    __syncthreads();
    // scan 512 bins, thread owns bin t; merge 4 replicas
    int p0 = pos[0][t], p1 = pos[1][t], p2 = pos[2][t], p3 = pos[3][t];
    int v = p0 + p1 + p2 + p3;
    int sc = v;
#pragma unroll
    for (int off = 1; off < 64; off <<= 1) {
        int o = __shfl_up(sc, off, 64);
        if (lane >= off) sc += o;
    }
    if (lane == 63) wsum[w] = sc;
    __syncthreads();
    int pre = 0;
#pragma unroll
    for (int i = 0; i < 8; i++) if (i < w) pre += wsum[i];
    int excl = sc + pre - v;
    sstart[t] = excl;
    lbase[t] = v ? atomicAdd(&bucketCnt[t], v) : 0;
    // per-replica base offsets within bin t (overwrite counters)
    pos[0][t] = 0;
    pos[1][t] = p0;
    pos[2][t] = p0 + p1;
    pos[3][t] = p0 + p1 + p2;
    __syncthreads();
#pragma unroll
    for (int k = 0; k < EPT; k++) {
        int m = meta[k];
        if (m >= 0) {
            int rr = m >> 22;
            int b  = (m >> 13) & 0x1FF;
            int o  = m & 0x1FFF;
            int idx = sstart[b] + pos[rr][b] + o;
            stage[idx]  = ent[k];
            stageB[idx] = (unsigned short)b;
        }
    }
    __syncthreads();
    for (int k = t; k < csize; k += PBLK) {
        int b = stageB[k];
        data[(unsigned int)b * CAPB + (unsigned int)(lbase[b] + (k - sstart[b]))] = stage[k];
    }
}

// Per-bucket one-pass counting sort (edges in registers via uint4 loads,
// x8 replicated bins, scatter straight to the L2-resident bucket region)
// + dinv + rs/re + fused node1 (u1 encoded fp8 e4m3 x64). BLK=512.
__global__ void k_sort_node1(unsigned int* __restrict__ data,
                             const int* __restrict__ bucketCnt,
                             const float4* __restrict__ x,
                             const float* __restrict__ Wemb, const float* __restrict__ bemb,
                             const float* __restrict__ W1,
                             int* __restrict__ rs, int* __restrict__ re,
                             float* __restrict__ dinv, uint4* __restrict__ u1q, int n) {
    __shared__ int pos[8][NPB], startl[NPB];    // 8 KB + 1 KB
    __shared__ int wsum[4];
    int b = blockIdx.x;
    int t = threadIdx.x;                        // 0..511
    int lane = t & 63;
    int rep = (lane >> 3) & 7;                  // x8 replica by 8-lane group
    int base = b * CAPB;
    int cnt = min(bucketCnt[b], CAPB);
#pragma unroll
    for (int z = 0; z < 4; z++) ((int*)pos)[t + z * SBLK] = 0;   // 8*256 ints
    __syncthreads();
    const uint4* data4 = (const uint4*)(data + base);   // base = b*9216, 16B aligned
    unsigned int ent[NIT4 * 4];                 // src (17 bits)
    int off[NIT4 * 4];                          // (rep<<22)|(dloc<<14)|o
#pragma unroll
    for (int it = 0; it < NIT4; it++) {
        int i4 = t + it * SBLK;                 // quad index
        int i = i4 * 4;
        uint4 p4 = (i < cnt) ? data4[i4] : make_uint4(0, 0, 0, 0);
#pragma unroll
        for (int k = 0; k < 4; k++) {
            int idx = it * 4 + k;
            if (i + k < cnt) {
                unsigned int p = ((const unsigned int*)&p4)[k];
                int dloc = (int)(p >> 17);
                int o = atomicAdd(&pos[rep][dloc], 1);
                ent[idx] = p & 0x1FFFF;
                off[idx] = (rep << 22) | (dloc << 14) | o;
            } else off[idx] = -1;
        }
    }
    __syncthreads();
    int node = b * NPB + t;
    float d = 0.0f;
    if (t < NPB) {
        int w = t >> 6;
        int p[8];
        int v = 0;
#pragma unroll
        for (int r = 0; r < 8; r++) { p[r] = pos[r][t]; v += p[r]; }
        int sc = v;
#pragma unroll
        for (int o = 1; o < 64; o <<= 1) {
            int s = __shfl_up(sc, o, 64);
            if (lane >= o) sc += s;
        }
        if (lane == 63) wsum[w] = sc;
        __syncthreads();
        int pre = 0;
#pragma unroll
        for (int i = 0; i < 4; i++) if (i < w) pre += wsum[i];
        int excl = sc + pre - v;
        startl[t] = excl;
        int run = 0;
#pragma unroll
        for (int r = 0; r < 8; r++) { pos[r][t] = run; run += p[r]; }
        if (node < n) {
            rs[node] = base + excl;
            re[node] = base + excl + v;
            d = rsqrtf((float)v + 1.0f);        // +1 self-loop
            dinv[node] = d;
        }
    } else {
        __syncthreads();
    }
    __syncthreads();
#pragma unroll
    for (int it = 0; it < NIT4 * 4; it++) {
        int m = off[it];
        if (m >= 0) {
            int rr = (m >> 22) & 7;
            int dl = (m >> 14) & 255;
            int o  = m & 0x3FFF;
            data[base + startl[dl] + pos[rr][dl] + o] = ent[it];
        }
    }
    if (t < NPB && node < n) {
        float4 xi = x[node];
        float h0[7];
#pragma unroll
        for (int j = 0; j < 4; j++) h0[j] = xi.x * Wemb[j] + bemb[j];
        h0[4] = xi.y; h0[5] = xi.z; h0[6] = xi.w;
        float s[16];
#pragma unroll
        for (int f = 0; f < 16; f++) {
            float tt = 0.0f;
#pragma unroll
            for (int j = 0; j < 7; j++) tt += h0[j] * W1[f * 7 + j];
            s[f] = tt * d * S8;                 // fp8 scale folded here
        }
        unsigned int w0, w1, w2, w3;
        w0 = __builtin_amdgcn_cvt_pk_fp8_f32(s[0],  s[1],  0,  false);
        w0 = __builtin_amdgcn_cvt_pk_fp8_f32(s[2],  s[3],  w0, true);
        w1 = __builtin_amdgcn_cvt_pk_fp8_f32(s[4],  s[5],  0,  false);
        w1 = __builtin_amdgcn_cvt_pk_fp8_f32(s[6],  s[7],  w1, true);
        w2 = __builtin_amdgcn_cvt_pk_fp8_f32(s[8],  s[9],  0,  false);
        w2 = __builtin_amdgcn_cvt_pk_fp8_f32(s[10], s[11], w2, true);
        w3 = __builtin_amdgcn_cvt_pk_fp8_f32(s[12], s[13], 0,  false);
        w3 = __builtin_amdgcn_cvt_pk_fp8_f32(s[14], s[15], w3, true);
        u1q[node] = make_uint4(w0, w1, w2, w3);
    }
}

typedef float vfloat2 __attribute__((vector_size(8)));   // cvt_pk_f32_fp8 return type

// fp8 e4m3 uint4 (16 msgs) decode-accumulate into f32[16]
__device__ __forceinline__ void dec16_add(uint4 q, float* acc) {
#pragma unroll
    for (int w = 0; w < 4; w++) {
        unsigned int u = ((const unsigned int*)&q)[w];
        vfloat2 lo = __builtin_amdgcn_cvt_pk_f32_fp8(u, false);
        vfloat2 hi = __builtin_amdgcn_cvt_pk_f32_fp8(u, true);
        acc[4 * w + 0] += lo[0]; acc[4 * w + 1] += lo[1];
        acc[4 * w + 2] += hi[0]; acc[4 * w + 3] += hi[1];
    }
}

// Layer 1: 4 adjacent lanes/node, lane j takes edges s+j, s+j+4, ...
// 4 gathers in flight; self/dinv loads hoisted. Partials via shfl_xor(1,2).
// Epilogue (all 4 lanes compute, j==0 stores):
// u2h = fp16((tanh(dinv/S8*acc+b1) @ W2^T) * dinv), one uint4 store.
__global__ void k_agg1(const unsigned int* __restrict__ sorted,
                       const int* __restrict__ rs, const int* __restrict__ re,
                       const uint4* __restrict__ u1q, const float* __restrict__ dinv,
                       const float* __restrict__ b1, const float* __restrict__ W2,
                       uint4* __restrict__ u2q, int n) {
    int tt = blockIdx.x * BLK + threadIdx.x;
    int node = tt >> 2;
    int j = tt & 3;
    if (node >= n) return;
    int s = rs[node], e = re[node];
    float d = dinv[node];                       // hoisted: issues early
    uint4 qs = make_uint4(0, 0, 0, 0);
    if (j == 0) qs = u1q[node];                 // hoisted self-loop load
    float acc[16];
#pragma unroll
    for (int k = 0; k < 16; k++) acc[k] = 0.0f;
    int i = s + j;
    for (; i + 12 < e; i += 16) {               // 4 gathers in flight
        uint4 q0 = u1q[sorted[i]];
        uint4 q1 = u1q[sorted[i + 4]];
        uint4 q2 = u1q[sorted[i + 8]];
        uint4 q3 = u1q[sorted[i + 12]];
        dec16_add(q0, acc);
        dec16_add(q1, acc);
        dec16_add(q2, acc);
        dec16_add(q3, acc);
    }
    for (; i + 4 < e; i += 8) {                 // 2 in flight
        uint4 q0 = u1q[sorted[i]];
        uint4 q1 = u1q[sorted[i + 4]];
        dec16_add(q0, acc);
        dec16_add(q1, acc);
    }
    if (i < e) {
        uint4 q = u1q[sorted[i]];
        dec16_add(q, acc);
    }
    if (j == 0) dec16_add(qs, acc);             // self-loop term, added once
#pragma unroll
    for (int k = 0; k < 16; k++) {
        acc[k] += __shfl_xor(acc[k], 1, 64);
        acc[k] += __shfl_xor(acc[k], 2, 64);
    }
    float dS = d * (1.0f / S8);                 // undo fp8 scale
    float h1[16];
#pragma unroll
    for (int k = 0; k < 16; k++) h1[k] = tanhf(dS * acc[k] + b1[k]);
    float r[8];
#pragma unroll
    for (int g = 0; g < 8; g++) {
        float ttv = 0.0f;
#pragma unroll
        for (int k = 0; k < 16; k++) ttv += h1[k] * W2[g * 16 + k];
        r[g] = ttv * d;
    }
    if (j == 0) {
        union { __half2 h2[4]; uint4 u4; } pk;
#pragma unroll
        for (int q = 0; q < 4; q++) pk.h2[q] = __floats2half2_rn(r[2 * q], r[2 * q + 1]);
        u2q[node] = pk.u4;
    }
}

__device__ __forceinline__ void h16_add(uint4 q, float* acc) {
    const __half2* p = (const __half2*)&q;
#pragma unroll
    for (int k = 0; k < 4; k++) {
        float2 a = __half22float2(p[k]);
        acc[2 * k]     += a.x;
        acc[2 * k + 1] += a.y;
    }
}

// Layer 2 + POOL fused: 4 adjacent lanes/node (16 nodes/wave), 4 gathers in
// flight; self/dinv/batch hoisted; partials via shfl_xor(1,2); h2 on base
// lanes; stride-4 wave-segmented reduction over sorted batch (offsets
// 4..32), segment heads atomicAdd 8 features + count into pooled/cnt.
__global__ void k_agg2_pool(const unsigned int* __restrict__ sorted,
                            const int* __restrict__ rs, const int* __restrict__ re,
                            const uint4* __restrict__ u2q, const float* __restrict__ dinv,
                            const float* __restrict__ b2, const int* __restrict__ batch,
                            float* __restrict__ pooled, float* __restrict__ cnt, int n) {
    int tt = blockIdx.x * BLK + threadIdx.x;
    int node = tt >> 2;
    int j = tt & 3;
    int lane = threadIdx.x & 63;
    bool valid = node < n;
    float h[8];
#pragma unroll
    for (int k = 0; k < 8; k++) h[k] = 0.0f;
    int g = -1;
    float c = 0.0f;
    if (valid) {
        int s = rs[node], e = re[node];
        float d = dinv[node];                   // hoisted
        uint4 qs = make_uint4(0, 0, 0, 0);
        int gq = 0;
        if (j == 0) {                           // hoisted self + batch loads
            qs = u2q[node];
            gq = batch[node];
        }
        float acc[8];
#pragma unroll
        for (int k = 0; k < 8; k++) acc[k] = 0.0f;
        int i = s + j;
        for (; i + 12 < e; i += 16) {           // 4 gathers in flight
            uint4 q0 = u2q[sorted[i]];
            uint4 q1 = u2q[sorted[i + 4]];
            uint4 q2 = u2q[sorted[i + 8]];
            uint4 q3 = u2q[sorted[i + 12]];
            h16_add(q0, acc);
            h16_add(q1, acc);
            h16_add(q2, acc);
            h16_add(q3, acc);
        }
        for (; i + 4 < e; i += 8) {             // 2 in flight
            uint4 q0 = u2q[sorted[i]];
            uint4 q1 = u2q[sorted[i + 4]];
            h16_add(q0, acc);
            h16_add(q1, acc);
        }
        if (i < e) {
            uint4 q = u2q[sorted[i]];
            h16_add(q, acc);
        }
        if (j == 0) h16_add(qs, acc);           // self-loop, added once
#pragma unroll
        for (int k = 0; k < 8; k++) {
            acc[k] += __shfl_xor(acc[k], 1, 64);
            acc[k] += __shfl_xor(acc[k], 2, 64);
        }
        if (j == 0) {
#pragma unroll
            for (int k = 0; k < 8; k++) h[k] = tanhf(d * acc[k] + b2[k]);
            g = gq;
            c = 1.0f;
        }
    }
    // stride-4 segmented reduction: base lanes (j==0) hold 16 consecutive
    // nodes per wave; offsets 4..32 only ever read base lanes.
#pragma unroll
    for (int off = 4; off < 64; off <<= 1) {
        int gn = __shfl_down(g, off, 64);
        float cn = __shfl_down(c, off, 64);
        float hn[8];
#pragma unroll
        for (int k = 0; k < 8; k++) hn[k] = __shfl_down(h[k], off, 64);
        bool take = (lane + off < 64) && (gn == g);
        if (take) {
            c += cn;
#pragma unroll
            for (int k = 0; k < 8; k++) h[k] += hn[k];
        }
    }
    int gprev = __shfl_up(g, 4, 64);
    bool head = valid && (j == 0) && (lane == 0 || gprev != g);
    if (head) {
#pragma unroll
        for (int k = 0; k < 8; k++) atomicAdd(&pooled[g * 8 + k], h[k]);
        atomicAdd(&cnt[g], c);
    }
}

// Tiny head: out[g] = dot(pooled[g], W3) / max(cnt,1) + b3
__global__ void k_out(const float* __restrict__ pooled, const float* __restrict__ cnt,
                      const float* __restrict__ W3, const float* __restrict__ b3,
                      float* __restrict__ out, int G) {
    int g = blockIdx.x * BLK + threadIdx.x;
    if (g >= G) return;
    float c = fmaxf(cnt[g], 1.0f);
    float t = 0.0f;
#pragma unroll
    for (int k = 0; k < 8; k++) t += pooled[g * 8 + k] * W3[k];
    out[g] = t / c + b3[0];
}

extern "C" void kernel_launch(void* const* d_in, const int* in_sizes, int n_in,
                              void* d_out, int out_size, void* d_ws, size_t ws_size,
                              hipStream_t stream) {
    const float* x    = (const float*)d_in[0];
    const int*   ei   = (const int*)d_in[1];
    const int*   batch= (const int*)d_in[2];
    const float* Wemb = (const float*)d_in[3];
    const float* bemb = (const float*)d_in[4];
    const float* W1   = (const float*)d_in[5];
    const float* b1   = (const float*)d_in[6];
    const float* W2   = (const float*)d_in[7];
    const float* b2   = (const float*)d_in[8];
    const float* W3   = (const float*)d_in[9];
    const float* b3   = (const float*)d_in[10];
    float* out = (float*)d_out;

    const int n = in_sizes[2];        // 100000
    const int E = in_sizes[1] / 2;    // 3200000
    const int G = out_size;           // 1024
    const int* row = ei;
    const int* col = ei + E;
    const int NB = (n + NPB - 1) / NPB;   // 391

    // workspace (4B words): dinv[n] | u1q(8n reserved, 4n used: fp8 16B/node) |
    //   u2h(4n) | rs[n] | re[n] | bucketCnt[NBMX] | pooled[8G] | cnt[G] |
    //   data[NB*CAPB]  (~20.5 MB)
    float* ws    = (float*)d_ws;
    float* dinv  = ws;                       // n
    uint4* u1q   = (uint4*)(ws + n);         // 4n words used (16 fp8/node)
    __half* u2h  = (__half*)(ws + 9 * n);    // 4n words (8 halves/node)
    int* rs      = (int*)(ws + 13 * n);      // n
    int* re      = rs + n;                   // n
    int* bucketCnt = re + n;                 // NBMX
    float* pooled  = (float*)(bucketCnt + NBMX);   // 8G
    float* cnt     = pooled + 8 * G;               // G
    unsigned int* data = (unsigned int*)(cnt + G); // NB*CAPB

    int gridP = (E + CAPS - 1) / CAPS;       // 521 blocks, chunk = 6144
    int gridA = (4 * n + BLK - 1) / BLK;     // 1563 blocks, 4 lanes/node

    // one memset zeroes bucketCnt + pooled + cnt (contiguous)
    hipMemsetAsync(bucketCnt, 0, (NBMX + 8 * G + G) * sizeof(int), stream);
    k_place<<<gridP, PBLK, 0, stream>>>((const int4*)row, (const int4*)col,
                                        bucketCnt, data, E, NB);
    k_sort_node1<<<NB, SBLK, 0, stream>>>(data, bucketCnt, (const float4*)x,
                                          Wemb, bemb, W1, rs, re, dinv, u1q, n);
    k_agg1<<<gridA, BLK, 0, stream>>>(data, rs, re, u1q,
                                      dinv, b1, W2, (uint4*)u2h, n);
    k_agg2_pool<<<gridA, BLK, 0, stream>>>(data, rs, re,
                                           (const uint4*)u2h, dinv, b2,
                                           batch, pooled, cnt, n);
    k_out<<<(G + BLK - 1) / BLK, BLK, 0, stream>>>(pooled, cnt, W3, b3, out, G);
}